// Round 15
// baseline (25.502 us; speedup 1.0000x reference)
//
#include <hip/hip_runtime.h>
#include <hip/hip_bf16.h>
#include <math.h>

#define NB 4
#define MA 256
#define NFS 128
#define KSEL 8
#define HID 256
#define NOUT 32
#define RCUT 5.0f
#define PI_F 3.14159265358979323846f

__device__ __forceinline__ float frcp(float x) { return __builtin_amdgcn_rcpf(x); }
__device__ __forceinline__ float fsqrt(float x) { return __builtin_amdgcn_sqrtf(x); }

// Kernel 1: 512 blocks = (rowgroup 0..255) x (half 0..1).
// Block computes 4 rows x 256 cols of (half==0 ? P : Q) over full f=0..127.
__global__ __launch_bounds__(256) void prep_kernel(
    const int* __restrict__ z, const float* __restrict__ r,
    const float* __restrict__ h, const float* __restrict__ Wa,
    const float* __restrict__ Wp1,
    float* __restrict__ out,
    float* __restrict__ a1, float* __restrict__ a2,
    float* __restrict__ P, float* __restrict__ Q) {
  const int b = blockIdx.x;
  const int half = b & 1;
  const int rg = b >> 1;
  const int r0 = 4 * rg;
  const int t = threadIdx.x;
  const int wave = t >> 6, lane = t & 63;
  const int c = t & 63, fq = t >> 6;

  __shared__ __align__(16) float hsh[4][NFS];
  __shared__ __align__(16) float psum[4][4][HID];   // 16 KB

  ((float2*)hsh)[t] = ((const float2*)(h + (size_t)r0 * NFS))[t];
  __syncthreads();

  if (half == 0) {
    const float h0 = hsh[wave][lane], h1 = hsh[wave][lane + 64];
    float p1 = h0 * Wa[lane]       + h1 * Wa[lane + 64];
    float p2 = h0 * Wa[NFS + lane] + h1 * Wa[NFS + lane + 64];
#pragma unroll
    for (int off = 32; off > 0; off >>= 1) {
      p1 += __shfl_down(p1, off);
      p2 += __shfl_down(p2, off);
    }
    if (lane == 0) { a1[r0 + wave] = p1; a2[r0 + wave] = p2; }
    if (t < 4)  out[r0 + t] = (float)z[r0 + t];
    if (t < 12) out[NB * MA + r0 * 3 + t] = r[r0 * 3 + t];
  }

  const float* __restrict__ Wbase = Wp1 + (size_t)(half ? NFS : 0) * HID;
  float4 acc[4] = {make_float4(0,0,0,0), make_float4(0,0,0,0),
                   make_float4(0,0,0,0), make_float4(0,0,0,0)};
#pragma unroll 4
  for (int ff = 0; ff < 32; ++ff) {
    const int f = fq * 32 + ff;
    const float4 w = *(const float4*)&Wbase[(size_t)f * HID + 4 * c];
#pragma unroll
    for (int rr = 0; rr < 4; ++rr) {
      const float hv = hsh[rr][f];
      acc[rr].x = fmaf(hv, w.x, acc[rr].x);
      acc[rr].y = fmaf(hv, w.y, acc[rr].y);
      acc[rr].z = fmaf(hv, w.z, acc[rr].z);
      acc[rr].w = fmaf(hv, w.w, acc[rr].w);
    }
  }
#pragma unroll
  for (int rr = 0; rr < 4; ++rr) *(float4*)&psum[fq][rr][4 * c] = acc[rr];
  __syncthreads();

  {
    const int r2 = t >> 6, c2 = t & 63;
    float4 s = *(const float4*)&psum[0][r2][4 * c2];
#pragma unroll
    for (int q = 1; q < 4; ++q) {
      const float4 p = *(const float4*)&psum[q][r2][4 * c2];
      s.x += p.x; s.y += p.y; s.z += p.z; s.w += p.w;
    }
    float* dst = (half ? Q : P) + (size_t)(r0 + r2) * HID + 4 * c2;
    *(float4*)dst = s;
  }
}

// compare-exchange for the rank sort: put (larger value | equal & smaller index) at a
#define CE8(a, b)                                                        \
  {                                                                      \
    const float va = sv[a], vb = sv[b];                                  \
    const int ja = sj[a], jb = sj[b];                                    \
    const bool sw = (vb > va) || (vb == va && jb < ja);                  \
    sv[a] = sw ? vb : va; sj[a] = sw ? jb : ja;                          \
    sv[b] = sw ? va : vb; sj[b] = sw ? ja : jb;                          \
  }

// Kernel 2: one block per (n,i). g(LDS) -> ballot binary-search top8 (zero DS) ->
// hidden -> layer2 broadcast -> final.
__global__ __launch_bounds__(256) void main_kernel(
    const int* __restrict__ z, const float* __restrict__ r,
    const float* __restrict__ a1g, const float* __restrict__ a2g,
    const float* __restrict__ ba,
    const float* __restrict__ Pg, const float* __restrict__ Qg,
    const float* __restrict__ bp1,
    const float* __restrict__ Wp2g, const float* __restrict__ bp2,
    float* __restrict__ out) {
  const int row = blockIdx.x;   // n*MA + i
  const int n = row >> 8;
  const int i = row & 255;
  const int tid = threadIdx.x;
  const int lane = tid & 63;

  __shared__ float gsh[MA];                            // 1 KB
  __shared__ __align__(16) float hid_sh[KSEL][HID];    // 8 KB
  __shared__ float psum2[8][KSEL][NOUT];               // 8 KB

  // layer-2 roles; one-pass Wp2 register staging issued EARLY (drains under g+topk)
  const int l2o = tid & 31;
  const int l2c = tid >> 5;
  float wreg[32];
#pragma unroll
  for (int j = 0; j < 32; ++j) wreg[j] = Wp2g[(size_t)(32 * l2c + j) * NOUT + l2o];

  // ---- g for all j (this thread's j = tid) ----
  const float rix = r[row * 3 + 0], riy = r[row * 3 + 1], riz = r[row * 3 + 2];
  {
    const int jg = n * MA + tid;
    const float dx = r[jg * 3 + 0] - rix;
    const float dy = r[jg * 3 + 1] - riy;
    const float dz = r[jg * 3 + 2] - riz;
    const float d = fsqrt(dx * dx + dy * dy + dz * dz);
    const int mi = (z[row] > -1) ? 1 : 0;
    const int mj = (z[jg] > -1) ? 1 : 0;
    const int mask = max(mi * mj - ((tid == i) ? 1 : 0), 0);
    float g = 0.0f;
    if (mask) {
      const float cf = 0.5f * (__cosf(PI_F * fminf(d, RCUT) / RCUT) + 1.0f);
      g = __expf(a1g[row] + cf * a2g[jg] + ba[0]);
    }
    gsh[tid] = g;
  }
  // hoisted independent loads (overlap with topk below)
  const float pi_h = Pg[(size_t)row * HID + tid];
  const float bb_h = bp1[tid];
  __syncthreads();

  // ---- ALL waves: denom (butterfly, unchanged) + top-8 via ballot binary search ----
  float att[KSEL];
  int   idx[KSEL];
  float qv[KSEL];
  {
    const float v0 = gsh[lane];
    const float v1 = gsh[lane + 64];
    const float v2 = gsh[lane + 128];
    const float v3 = gsh[lane + 192];
    float s = (v0 + v1) + (v2 + v3);
#pragma unroll
    for (int off = 32; off > 0; off >>= 1) s += __shfl_xor(s, off);
    const float rden = frcp(fmaxf(s, 1e-8f));

    // count of values strictly greater than t (all 256 via 4 ballots)
    #define CGT(t) (__popcll(__ballot(v0 > (t))) + __popcll(__ballot(v1 > (t))) + \
                    __popcll(__ballot(v2 > (t))) + __popcll(__ballot(v3 > (t))))

    const int cpos = CGT(0.0f);
    float V8;
    if (cpos >= 8) {
      // binary search bit space of positive finite floats for the 8th-largest value
      unsigned lo = 0u, hi = 0x7f800000u;   // f(lo)=cpos>=8, f(inf)=0<8
#pragma unroll 1
      for (int it = 0; it < 31; ++it) {
        const unsigned mid = (lo + hi) >> 1;
        if (mid == lo) break;
        const int c = CGT(__uint_as_float(mid));
        if (c >= 8) lo = mid; else hi = mid;
      }
      V8 = __uint_as_float(hi);             // exact 8th-largest value
    } else {
      V8 = 0.0f;                            // fewer than 8 positive -> ties at zero
    }
    const int m = CGT(V8);                  // strict winners (<= 7)
    #undef CGT

    unsigned long long s0 = __ballot(v0 > V8), s1 = __ballot(v1 > V8);
    unsigned long long s2 = __ballot(v2 > V8), s3 = __ballot(v3 > V8);
    unsigned long long t0 = __ballot(v0 == V8), t1 = __ballot(v1 == V8);
    unsigned long long t2 = __ballot(v2 == V8), t3 = __ballot(v3 == V8);

    // take the (8-m) lowest-index ties, slot-major (global index = lane + 64*slot)
    int need = 8 - m;
#pragma unroll
    for (int b = 0; b < 8; ++b) { if (need > 0 && t0) { s0 |= t0 & (~t0 + 1ull); t0 &= t0 - 1ull; --need; } }
#pragma unroll
    for (int b = 0; b < 8; ++b) { if (need > 0 && t1) { s1 |= t1 & (~t1 + 1ull); t1 &= t1 - 1ull; --need; } }
#pragma unroll
    for (int b = 0; b < 8; ++b) { if (need > 0 && t2) { s2 |= t2 & (~t2 + 1ull); t2 &= t2 - 1ull; --need; } }
#pragma unroll
    for (int b = 0; b < 8; ++b) { if (need > 0 && t3) { s3 |= t3 & (~t3 + 1ull); t3 &= t3 - 1ull; --need; } }

    // extract the 8 (value, index) pairs via uniform readlane (zero DS ops)
    float sv[8]; int sj[8];
#pragma unroll
    for (int e = 0; e < 8; ++e) {
      const int slot = s0 ? 0 : (s1 ? 1 : (s2 ? 2 : 3));
      const unsigned long long mm = (slot == 0) ? s0 : (slot == 1) ? s1 : (slot == 2) ? s2 : s3;
      const int l = (int)__builtin_ctzll(mm);
      const float vsel = (slot == 0) ? v0 : (slot == 1) ? v1 : (slot == 2) ? v2 : v3;
      sv[e] = __int_as_float(__builtin_amdgcn_readlane(__float_as_int(vsel), l));
      sj[e] = l + (slot << 6);
      if (slot == 0) s0 &= s0 - 1ull;
      else if (slot == 1) s1 &= s1 - 1ull;
      else if (slot == 2) s2 &= s2 - 1ull;
      else s3 &= s3 - 1ull;
    }

    // rank by (value desc, index asc): 19-CE Batcher network, static indices
    CE8(0, 1) CE8(2, 3) CE8(4, 5) CE8(6, 7)
    CE8(0, 2) CE8(1, 3) CE8(4, 6) CE8(5, 7)
    CE8(1, 2) CE8(5, 6)
    CE8(0, 4) CE8(1, 5) CE8(2, 6) CE8(3, 7)
    CE8(2, 4) CE8(3, 5)
    CE8(1, 2) CE8(3, 4) CE8(5, 6)

#pragma unroll
    for (int k = 0; k < KSEL; ++k) {
      att[k] = sv[k] * rden;
      idx[k] = __builtin_amdgcn_readfirstlane(sj[k]);
      qv[k] = Qg[(size_t)(n * MA + idx[k]) * HID + tid];   // prefetch
    }
  }

  // ---- hidden: hid[k][tid] = silu(att_k*(P+Q) + b) ----
  {
#pragma unroll
    for (int k = 0; k < KSEL; k++) {
      const float x = att[k] * (pi_h + qv[k]) + bb_h;
      hid_sh[k][tid] = x * frcp(1.0f + __expf(-x));
    }
  }
  __syncthreads();

  // ---- layer 2, broadcast scheme ----
  {
    float acc[KSEL];
#pragma unroll
    for (int k = 0; k < KSEL; ++k) acc[k] = 0.0f;
#pragma unroll
    for (int k = 0; k < KSEL; ++k) {
      const float4* __restrict__ hrow = (const float4*)&hid_sh[k][32 * l2c];
#pragma unroll
      for (int j4 = 0; j4 < 8; ++j4) {
        const float4 hv = hrow[j4];    // uniform across 32-lane group -> broadcast
        acc[k] = fmaf(hv.x, wreg[4 * j4 + 0],
                 fmaf(hv.y, wreg[4 * j4 + 1],
                 fmaf(hv.z, wreg[4 * j4 + 2],
                 fmaf(hv.w, wreg[4 * j4 + 3], acc[k]))));
      }
    }
#pragma unroll
    for (int k = 0; k < KSEL; ++k) psum2[l2c][k][l2o] = acc[k];
  }
  __syncthreads();

  // ---- final: thread (k2 = tid>>5, o = tid&31); select-tree idx; rcp norm ----
  {
    const int k2 = tid >> 5;
    const int o = tid & 31;
    float s = bp2[o];
#pragma unroll
    for (int cc = 0; cc < 8; ++cc) s += psum2[cc][k2][o];
    const int j01 = (k2 & 1) ? idx[1] : idx[0];
    const int j23 = (k2 & 1) ? idx[3] : idx[2];
    const int j45 = (k2 & 1) ? idx[5] : idx[4];
    const int j67 = (k2 & 1) ? idx[7] : idx[6];
    const int j03 = (k2 & 2) ? j23 : j01;
    const int j47 = (k2 & 2) ? j67 : j45;
    const int jsel = (k2 & 4) ? j47 : j03;
    const int jg = n * MA + jsel;
    const float dx = r[jg * 3 + 0] - rix;
    const float dy = r[jg * 3 + 1] - riy;
    const float dz = r[jg * 3 + 2] - riz;
    const float rn = frcp(fmaxf(fsqrt(dx * dx + dy * dy + dz * dz), 1e-4f));
    float* cb = out + NB * MA + NB * MA * 3 +
                ((size_t)row * KSEL + k2) * (NOUT * 3) + o * 3;
    cb[0] = s * (dx * rn);
    cb[1] = s * (dy * rn);
    cb[2] = s * (dz * rn);
  }
}

extern "C" void kernel_launch(void* const* d_in, const int* in_sizes, int n_in,
                              void* d_out, int out_size, void* d_ws, size_t ws_size,
                              hipStream_t stream) {
  const int*   z   = (const int*)d_in[0];
  const float* r   = (const float*)d_in[1];
  const float* h   = (const float*)d_in[2];
  const float* Wa  = (const float*)d_in[3];
  const float* ba  = (const float*)d_in[4];
  const float* Wp1 = (const float*)d_in[5];
  const float* bp1 = (const float*)d_in[6];
  const float* Wp2 = (const float*)d_in[7];
  const float* bp2 = (const float*)d_in[8];
  float* out = (float*)d_out;

  float* a1 = (float*)d_ws;                 // 1024
  float* a2 = a1 + NB * MA;                 // 1024
  float* P  = a2 + NB * MA;                 // 1024*256
  float* Q  = P + (size_t)NB * MA * HID;    // 1024*256

  prep_kernel<<<2 * NB * MA / 4, 256, 0, stream>>>(z, r, h, Wa, Wp1, out, a1, a2, P, Q);
  main_kernel<<<NB * MA, 256, 0, stream>>>(z, r, a1, a2, ba, P, Q, bp1, Wp2, bp2, out);
}

// Round 16
// 21.353 us; speedup vs baseline: 1.1943x; 1.1943x over previous
//
#include <hip/hip_runtime.h>
#include <hip/hip_bf16.h>
#include <math.h>

#define NB 4
#define MA 256
#define NFS 128
#define KSEL 8
#define HID 256
#define NOUT 32
#define RCUT 5.0f
#define PI_F 3.14159265358979323846f

__device__ __forceinline__ float frcp(float x) { return __builtin_amdgcn_rcpf(x); }
__device__ __forceinline__ float fsqrt(float x) { return __builtin_amdgcn_sqrtf(x); }

// value-only compare-exchange: x <- max, y <- min
#define VCE(x, y) { const float _mx = fmaxf(x, y); y = fminf(x, y); x = _mx; }

// Kernel 1: 512 blocks = (rowgroup 0..255) x (half 0..1).
// Block computes 4 rows x 256 cols of (half==0 ? P : Q) over full f=0..127.
__global__ __launch_bounds__(256) void prep_kernel(
    const int* __restrict__ z, const float* __restrict__ r,
    const float* __restrict__ h, const float* __restrict__ Wa,
    const float* __restrict__ Wp1,
    float* __restrict__ out,
    float* __restrict__ a1, float* __restrict__ a2,
    float* __restrict__ P, float* __restrict__ Q) {
  const int b = blockIdx.x;
  const int half = b & 1;
  const int rg = b >> 1;
  const int r0 = 4 * rg;
  const int t = threadIdx.x;
  const int wave = t >> 6, lane = t & 63;
  const int c = t & 63, fq = t >> 6;

  __shared__ __align__(16) float hsh[4][NFS];
  __shared__ __align__(16) float psum[4][4][HID];   // 16 KB

  ((float2*)hsh)[t] = ((const float2*)(h + (size_t)r0 * NFS))[t];
  __syncthreads();

  if (half == 0) {
    const float h0 = hsh[wave][lane], h1 = hsh[wave][lane + 64];
    float p1 = h0 * Wa[lane]       + h1 * Wa[lane + 64];
    float p2 = h0 * Wa[NFS + lane] + h1 * Wa[NFS + lane + 64];
#pragma unroll
    for (int off = 32; off > 0; off >>= 1) {
      p1 += __shfl_down(p1, off);
      p2 += __shfl_down(p2, off);
    }
    if (lane == 0) { a1[r0 + wave] = p1; a2[r0 + wave] = p2; }
    if (t < 4)  out[r0 + t] = (float)z[r0 + t];
    if (t < 12) out[NB * MA + r0 * 3 + t] = r[r0 * 3 + t];
  }

  const float* __restrict__ Wbase = Wp1 + (size_t)(half ? NFS : 0) * HID;
  float4 acc[4] = {make_float4(0,0,0,0), make_float4(0,0,0,0),
                   make_float4(0,0,0,0), make_float4(0,0,0,0)};
#pragma unroll 4
  for (int ff = 0; ff < 32; ++ff) {
    const int f = fq * 32 + ff;
    const float4 w = *(const float4*)&Wbase[(size_t)f * HID + 4 * c];
#pragma unroll
    for (int rr = 0; rr < 4; ++rr) {
      const float hv = hsh[rr][f];
      acc[rr].x = fmaf(hv, w.x, acc[rr].x);
      acc[rr].y = fmaf(hv, w.y, acc[rr].y);
      acc[rr].z = fmaf(hv, w.z, acc[rr].z);
      acc[rr].w = fmaf(hv, w.w, acc[rr].w);
    }
  }
#pragma unroll
  for (int rr = 0; rr < 4; ++rr) *(float4*)&psum[fq][rr][4 * c] = acc[rr];
  __syncthreads();

  {
    const int r2 = t >> 6, c2 = t & 63;
    float4 s = *(const float4*)&psum[0][r2][4 * c2];
#pragma unroll
    for (int q = 1; q < 4; ++q) {
      const float4 p = *(const float4*)&psum[q][r2][4 * c2];
      s.x += p.x; s.y += p.y; s.z += p.z; s.w += p.w;
    }
    float* dst = (half ? Q : P) + (size_t)(r0 + r2) * HID + 4 * c2;
    *(float4*)dst = s;
  }
}

// Kernel 2: one block per (n,i). g(LDS) -> bitonic-merge top8 (6-level chain) ->
// hidden -> layer2 broadcast -> final. Everything else identical to the 19.56us base.
__global__ __launch_bounds__(256) void main_kernel(
    const int* __restrict__ z, const float* __restrict__ r,
    const float* __restrict__ a1g, const float* __restrict__ a2g,
    const float* __restrict__ ba,
    const float* __restrict__ Pg, const float* __restrict__ Qg,
    const float* __restrict__ bp1,
    const float* __restrict__ Wp2g, const float* __restrict__ bp2,
    float* __restrict__ out) {
  const int row = blockIdx.x;   // n*MA + i
  const int n = row >> 8;
  const int i = row & 255;
  const int tid = threadIdx.x;
  const int lane = tid & 63;

  __shared__ float gsh[MA];                            // 1 KB
  __shared__ __align__(16) float hid_sh[KSEL][HID];    // 8 KB
  __shared__ float psum2[8][KSEL][NOUT];               // 8 KB

  // layer-2 roles; one-pass Wp2 register staging issued EARLY (drains under g+topk)
  const int l2o = tid & 31;
  const int l2c = tid >> 5;
  float wreg[32];
#pragma unroll
  for (int j = 0; j < 32; ++j) wreg[j] = Wp2g[(size_t)(32 * l2c + j) * NOUT + l2o];

  // ---- g for all j (this thread's j = tid) ----
  const float rix = r[row * 3 + 0], riy = r[row * 3 + 1], riz = r[row * 3 + 2];
  {
    const int jg = n * MA + tid;
    const float dx = r[jg * 3 + 0] - rix;
    const float dy = r[jg * 3 + 1] - riy;
    const float dz = r[jg * 3 + 2] - riz;
    const float d = fsqrt(dx * dx + dy * dy + dz * dz);
    const int mi = (z[row] > -1) ? 1 : 0;
    const int mj = (z[jg] > -1) ? 1 : 0;
    const int mask = max(mi * mj - ((tid == i) ? 1 : 0), 0);
    float g = 0.0f;
    if (mask) {
      const float cf = 0.5f * (__cosf(PI_F * fminf(d, RCUT) / RCUT) + 1.0f);
      g = __expf(a1g[row] + cf * a2g[jg] + ba[0]);
    }
    gsh[tid] = g;
  }
  // hoisted independent loads (overlap with topk below)
  const float pi_h = Pg[(size_t)row * HID + tid];
  const float bb_h = bp1[tid];
  __syncthreads();

  // ---- ALL waves: denom (butterfly) + top-8 via bitonic merge-reduction ----
  float att[KSEL];
  int   idx[KSEL];
  float qv[KSEL];
  {
    const float v0 = gsh[lane];
    const float v1 = gsh[lane + 64];
    const float v2 = gsh[lane + 128];
    const float v3 = gsh[lane + 192];
    float s = (v0 + v1) + (v2 + v3);
#pragma unroll
    for (int off = 32; off > 0; off >>= 1) s += __shfl_xor(s, off);
    const float rden = frcp(fmaxf(s, 1e-8f));

    // local sort-4 desc (values only), pad with -1 sentinels (all real g >= 0)
    float e0 = v0, e1 = v1, e2 = v2, e3 = v3;
    VCE(e0, e1) VCE(e2, e3) VCE(e0, e2) VCE(e1, e3) VCE(e1, e2)
    float e4 = -1.0f, e5 = -1.0f, e6 = -1.0f, e7 = -1.0f;

    // 6 xor-butterfly levels; each: 8 independent shfl + bitonic merge keep-top-8
#pragma unroll
    for (int off = 1; off <= 32; off <<= 1) {
      const float p0 = __shfl_xor(e0, off), p1 = __shfl_xor(e1, off);
      const float p2 = __shfl_xor(e2, off), p3 = __shfl_xor(e3, off);
      const float p4 = __shfl_xor(e4, off), p5 = __shfl_xor(e5, off);
      const float p6 = __shfl_xor(e6, off), p7 = __shfl_xor(e7, off);
      float m0 = fmaxf(e0, p7), m1 = fmaxf(e1, p6);
      float m2 = fmaxf(e2, p5), m3 = fmaxf(e3, p4);
      float m4 = fmaxf(e4, p3), m5 = fmaxf(e5, p2);
      float m6 = fmaxf(e6, p1), m7 = fmaxf(e7, p0);
      VCE(m0, m4) VCE(m1, m5) VCE(m2, m6) VCE(m3, m7)
      VCE(m0, m2) VCE(m1, m3) VCE(m4, m6) VCE(m5, m7)
      VCE(m0, m1) VCE(m2, m3) VCE(m4, m5) VCE(m6, m7)
      e0 = m0; e1 = m1; e2 = m2; e3 = m3;
      e4 = m4; e5 = m5; e6 = m6; e7 = m7;
    }

    // index recovery: for each sorted value, cnt-th equal element in ascending
    // global index order (slot-major = ascending j). Matches lax.top_k ties.
    const float V[8] = {e0, e1, e2, e3, e4, e5, e6, e7};
    int cnt = 0;
    float prev = -2.0f;
#pragma unroll
    for (int k = 0; k < KSEL; ++k) {
      cnt = (V[k] == prev) ? cnt + 1 : 0;
      prev = V[k];
      const unsigned long long b0 = __ballot(v0 == V[k]);
      const unsigned long long b1 = __ballot(v1 == V[k]);
      const unsigned long long b2 = __ballot(v2 == V[k]);
      const unsigned long long b3 = __ballot(v3 == V[k]);
      const int c0 = __popcll(b0), c1 = __popcll(b1), c2 = __popcll(b2);
      unsigned long long m; int base; int rem = cnt;
      if (rem < c0) { m = b0; base = 0; }
      else if (rem < c0 + c1) { m = b1; base = 64; rem -= c0; }
      else if (rem < c0 + c1 + c2) { m = b2; base = 128; rem -= c0 + c1; }
      else { m = b3; base = 192; rem -= c0 + c1 + c2; }
#pragma unroll
      for (int t = 0; t < 7; ++t) if (t < rem) m &= m - 1ull;
      idx[k] = base + (int)__builtin_ctzll(m);
      att[k] = V[k] * rden;
    }
#pragma unroll
    for (int k = 0; k < KSEL; ++k)
      qv[k] = Qg[(size_t)(n * MA + idx[k]) * HID + tid];
  }

  // ---- hidden: hid[k][tid] = silu(att_k*(P+Q) + b) ----
  {
#pragma unroll
    for (int k = 0; k < KSEL; k++) {
      const float x = att[k] * (pi_h + qv[k]) + bb_h;
      hid_sh[k][tid] = x * frcp(1.0f + __expf(-x));
    }
  }
  __syncthreads();

  // ---- layer 2, broadcast scheme ----
  {
    float acc[KSEL];
#pragma unroll
    for (int k = 0; k < KSEL; ++k) acc[k] = 0.0f;
#pragma unroll
    for (int k = 0; k < KSEL; ++k) {
      const float4* __restrict__ hrow = (const float4*)&hid_sh[k][32 * l2c];
#pragma unroll
      for (int j4 = 0; j4 < 8; ++j4) {
        const float4 hv = hrow[j4];    // uniform across 32-lane group -> broadcast
        acc[k] = fmaf(hv.x, wreg[4 * j4 + 0],
                 fmaf(hv.y, wreg[4 * j4 + 1],
                 fmaf(hv.z, wreg[4 * j4 + 2],
                 fmaf(hv.w, wreg[4 * j4 + 3], acc[k]))));
      }
    }
#pragma unroll
    for (int k = 0; k < KSEL; ++k) psum2[l2c][k][l2o] = acc[k];
  }
  __syncthreads();

  // ---- final: thread (k2 = tid>>5, o = tid&31); select-tree idx; rcp norm ----
  {
    const int k2 = tid >> 5;
    const int o = tid & 31;
    float s = bp2[o];
#pragma unroll
    for (int cc = 0; cc < 8; ++cc) s += psum2[cc][k2][o];
    const int j01 = (k2 & 1) ? idx[1] : idx[0];
    const int j23 = (k2 & 1) ? idx[3] : idx[2];
    const int j45 = (k2 & 1) ? idx[5] : idx[4];
    const int j67 = (k2 & 1) ? idx[7] : idx[6];
    const int j03 = (k2 & 2) ? j23 : j01;
    const int j47 = (k2 & 2) ? j67 : j45;
    const int jsel = (k2 & 4) ? j47 : j03;
    const int jg = n * MA + jsel;
    const float dx = r[jg * 3 + 0] - rix;
    const float dy = r[jg * 3 + 1] - riy;
    const float dz = r[jg * 3 + 2] - riz;
    const float rn = frcp(fmaxf(fsqrt(dx * dx + dy * dy + dz * dz), 1e-4f));
    float* cb = out + NB * MA + NB * MA * 3 +
                ((size_t)row * KSEL + k2) * (NOUT * 3) + o * 3;
    cb[0] = s * (dx * rn);
    cb[1] = s * (dy * rn);
    cb[2] = s * (dz * rn);
  }
}

extern "C" void kernel_launch(void* const* d_in, const int* in_sizes, int n_in,
                              void* d_out, int out_size, void* d_ws, size_t ws_size,
                              hipStream_t stream) {
  const int*   z   = (const int*)d_in[0];
  const float* r   = (const float*)d_in[1];
  const float* h   = (const float*)d_in[2];
  const float* Wa  = (const float*)d_in[3];
  const float* ba  = (const float*)d_in[4];
  const float* Wp1 = (const float*)d_in[5];
  const float* bp1 = (const float*)d_in[6];
  const float* Wp2 = (const float*)d_in[7];
  const float* bp2 = (const float*)d_in[8];
  float* out = (float*)d_out;

  float* a1 = (float*)d_ws;                 // 1024
  float* a2 = a1 + NB * MA;                 // 1024
  float* P  = a2 + NB * MA;                 // 1024*256
  float* Q  = P + (size_t)NB * MA * HID;    // 1024*256

  prep_kernel<<<2 * NB * MA / 4, 256, 0, stream>>>(z, r, h, Wa, Wp1, out, a1, a2, P, Q);
  main_kernel<<<NB * MA, 256, 0, stream>>>(z, r, a1, a2, ba, P, Q, bp1, Wp2, bp2, out);
}

// Round 17
// 19.827 us; speedup vs baseline: 1.2862x; 1.0770x over previous
//
#include <hip/hip_runtime.h>
#include <hip/hip_bf16.h>
#include <math.h>

#define NB 4
#define MA 256
#define NFS 128
#define KSEL 8
#define HID 256
#define NOUT 32
#define RCUT 5.0f
#define PI_F 3.14159265358979323846f

__device__ __forceinline__ float frcp(float x) { return __builtin_amdgcn_rcpf(x); }
__device__ __forceinline__ float fsqrt(float x) { return __builtin_amdgcn_sqrtf(x); }

// Kernel 1: 512 blocks = (rowgroup 0..255) x (half 0..1).
// Block computes 4 rows x 256 cols of (half==0 ? P : Q) over full f=0..127.
// half==0 blocks also emit a1/a2, z/r copy, and packed r4 = (rx,ry,rz,mask).
__global__ __launch_bounds__(256) void prep_kernel(
    const int* __restrict__ z, const float* __restrict__ r,
    const float* __restrict__ h, const float* __restrict__ Wa,
    const float* __restrict__ Wp1,
    float* __restrict__ out,
    float* __restrict__ a1, float* __restrict__ a2,
    float* __restrict__ P, float* __restrict__ Q,
    float4* __restrict__ r4) {
  const int b = blockIdx.x;
  const int half = b & 1;
  const int rg = b >> 1;
  const int r0 = 4 * rg;
  const int t = threadIdx.x;
  const int wave = t >> 6, lane = t & 63;
  const int c = t & 63, fq = t >> 6;

  __shared__ __align__(16) float hsh[4][NFS];
  __shared__ __align__(16) float psum[4][4][HID];   // 16 KB

  ((float2*)hsh)[t] = ((const float2*)(h + (size_t)r0 * NFS))[t];
  __syncthreads();

  if (half == 0) {
    const float h0 = hsh[wave][lane], h1 = hsh[wave][lane + 64];
    float p1 = h0 * Wa[lane]       + h1 * Wa[lane + 64];
    float p2 = h0 * Wa[NFS + lane] + h1 * Wa[NFS + lane + 64];
#pragma unroll
    for (int off = 32; off > 0; off >>= 1) {
      p1 += __shfl_down(p1, off);
      p2 += __shfl_down(p2, off);
    }
    if (lane == 0) { a1[r0 + wave] = p1; a2[r0 + wave] = p2; }
    if (t < 4) {
      const int rr = r0 + t;
      out[rr] = (float)z[rr];
      r4[rr] = make_float4(r[rr * 3 + 0], r[rr * 3 + 1], r[rr * 3 + 2],
                           (z[rr] > -1) ? 1.0f : 0.0f);
    }
    if (t < 12) out[NB * MA + r0 * 3 + t] = r[r0 * 3 + t];
  }

  const float* __restrict__ Wbase = Wp1 + (size_t)(half ? NFS : 0) * HID;
  float4 acc[4] = {make_float4(0,0,0,0), make_float4(0,0,0,0),
                   make_float4(0,0,0,0), make_float4(0,0,0,0)};
#pragma unroll 4
  for (int ff = 0; ff < 32; ++ff) {
    const int f = fq * 32 + ff;
    const float4 w = *(const float4*)&Wbase[(size_t)f * HID + 4 * c];
#pragma unroll
    for (int rr = 0; rr < 4; ++rr) {
      const float hv = hsh[rr][f];
      acc[rr].x = fmaf(hv, w.x, acc[rr].x);
      acc[rr].y = fmaf(hv, w.y, acc[rr].y);
      acc[rr].z = fmaf(hv, w.z, acc[rr].z);
      acc[rr].w = fmaf(hv, w.w, acc[rr].w);
    }
  }
#pragma unroll
  for (int rr = 0; rr < 4; ++rr) *(float4*)&psum[fq][rr][4 * c] = acc[rr];
  __syncthreads();

  {
    const int r2 = t >> 6, c2 = t & 63;
    float4 s = *(const float4*)&psum[0][r2][4 * c2];
#pragma unroll
    for (int q = 1; q < 4; ++q) {
      const float4 p = *(const float4*)&psum[q][r2][4 * c2];
      s.x += p.x; s.y += p.y; s.z += p.z; s.w += p.w;
    }
    float* dst = (half ? Q : P) + (size_t)(r0 + r2) * HID + 4 * c2;
    *(float4*)dst = s;
  }
}

// Kernel 2: one block per (n,i). g (r4, 2 VMEM) -> all-wave ballot top8 ->
// hidden -> layer2 broadcast -> final (select tree). Structure = the 19.56us base.
__global__ __launch_bounds__(256) void main_kernel(
    const float4* __restrict__ r4g,
    const float* __restrict__ a1g, const float* __restrict__ a2g,
    const float* __restrict__ ba,
    const float* __restrict__ Pg, const float* __restrict__ Qg,
    const float* __restrict__ bp1,
    const float* __restrict__ Wp2g, const float* __restrict__ bp2,
    float* __restrict__ out) {
  const int row = blockIdx.x;   // n*MA + i
  const int n = row >> 8;
  const int i = row & 255;
  const int tid = threadIdx.x;
  const int lane = tid & 63;

  __shared__ float gsh[MA];                            // 1 KB
  __shared__ __align__(16) float hid_sh[KSEL][HID];    // 8 KB
  __shared__ float psum2[8][KSEL][NOUT];               // 8 KB

  // layer-2 roles; one-pass Wp2 register staging issued EARLY (drains under g+topk)
  const int l2o = tid & 31;
  const int l2c = tid >> 5;
  float wreg[32];
#pragma unroll
  for (int j = 0; j < 32; ++j) wreg[j] = Wp2g[(size_t)(32 * l2c + j) * NOUT + l2o];

  // ---- g for all j (this thread's j = tid): 2 VMEM (r4 + a2) ----
  const float4 ri4 = r4g[row];
  const float rix = ri4.x, riy = ri4.y, riz = ri4.z;
  {
    const int jg = n * MA + tid;
    const float4 rj4 = r4g[jg];
    const float dx = rj4.x - rix;
    const float dy = rj4.y - riy;
    const float dz = rj4.z - riz;
    const float d = fsqrt(dx * dx + dy * dy + dz * dz);
    float g = 0.0f;
    if (ri4.w * rj4.w > 0.5f && tid != i) {
      const float cf = 0.5f * (__cosf(PI_F * fminf(d, RCUT) / RCUT) + 1.0f);
      g = __expf(a1g[row] + cf * a2g[jg] + ba[0]);
    }
    gsh[tid] = g;
  }
  // hoisted independent loads (overlap with topk chain below)
  const float pi_h = Pg[(size_t)row * HID + tid];
  const float bb_h = bp1[tid];
  __syncthreads();

  // ---- ALL waves: denom + top-8; value-only butterfly + ballot index recovery ----
  float att[KSEL];
  int   idx[KSEL];
  {
    float v0 = gsh[lane];
    float v1 = gsh[lane + 64];
    float v2 = gsh[lane + 128];
    float v3 = gsh[lane + 192];
    float s = (v0 + v1) + (v2 + v3);
#pragma unroll
    for (int off = 32; off > 0; off >>= 1) s += __shfl_xor(s, off);
    const float rden = frcp(fmaxf(s, 1e-8f));
#pragma unroll
    for (int k = 0; k < KSEL; k++) {
      float bv = fmaxf(fmaxf(v0, v1), fmaxf(v2, v3));
#pragma unroll
      for (int off = 32; off > 0; off >>= 1) bv = fmaxf(bv, __shfl_xor(bv, off));
      const unsigned long long b0 = __ballot(v0 == bv);
      const unsigned long long b1 = __ballot(v1 == bv);
      const unsigned long long b2 = __ballot(v2 == bv);
      const unsigned long long b3 = __ballot(v3 == bv);
      const int j0 = b0 ? __builtin_ctzll(b0)       : 1024;
      const int j1 = b1 ? __builtin_ctzll(b1) + 64  : 1024;
      const int j2 = b2 ? __builtin_ctzll(b2) + 128 : 1024;
      const int j3 = b3 ? __builtin_ctzll(b3) + 192 : 1024;
      const int bi = min(min(j0, j1), min(j2, j3));
      att[k] = bv * rden;
      idx[k] = __builtin_amdgcn_readfirstlane(bi);
      const int slot = bi >> 6, who = bi & 63;
      if (lane == who) {
        if (slot == 0) v0 = -1.0f;
        else if (slot == 1) v1 = -1.0f;
        else if (slot == 2) v2 = -1.0f;
        else v3 = -1.0f;
      }
    }
  }

  // ---- hidden: hid[k][tid] = silu(att_k*(P+Q) + b) with rcp-silu ----
  {
#pragma unroll
    for (int k = 0; k < KSEL; k++) {
      const float q = Qg[(size_t)(n * MA + idx[k]) * HID + tid];
      const float x = att[k] * (pi_h + q) + bb_h;
      hid_sh[k][tid] = x * frcp(1.0f + __expf(-x));
    }
  }
  __syncthreads();

  // ---- layer 2, broadcast scheme ----
  {
    float acc[KSEL];
#pragma unroll
    for (int k = 0; k < KSEL; ++k) acc[k] = 0.0f;
#pragma unroll
    for (int k = 0; k < KSEL; ++k) {
      const float4* __restrict__ hrow = (const float4*)&hid_sh[k][32 * l2c];
#pragma unroll
      for (int j4 = 0; j4 < 8; ++j4) {
        const float4 hv = hrow[j4];    // uniform across 32-lane group -> broadcast
        acc[k] = fmaf(hv.x, wreg[4 * j4 + 0],
                 fmaf(hv.y, wreg[4 * j4 + 1],
                 fmaf(hv.z, wreg[4 * j4 + 2],
                 fmaf(hv.w, wreg[4 * j4 + 3], acc[k]))));
      }
    }
#pragma unroll
    for (int k = 0; k < KSEL; ++k) psum2[l2c][k][l2o] = acc[k];
  }
  __syncthreads();

  // ---- final: thread (k2 = tid>>5, o = tid&31); select-tree idx; rcp norm ----
  {
    const int k2 = tid >> 5;
    const int o = tid & 31;
    float s = bp2[o];
#pragma unroll
    for (int cc = 0; cc < 8; ++cc) s += psum2[cc][k2][o];
    const int j01 = (k2 & 1) ? idx[1] : idx[0];
    const int j23 = (k2 & 1) ? idx[3] : idx[2];
    const int j45 = (k2 & 1) ? idx[5] : idx[4];
    const int j67 = (k2 & 1) ? idx[7] : idx[6];
    const int j03 = (k2 & 2) ? j23 : j01;
    const int j47 = (k2 & 2) ? j67 : j45;
    const int jsel = (k2 & 4) ? j47 : j03;
    const float4 rj4 = r4g[n * MA + jsel];
    const float dx = rj4.x - rix;
    const float dy = rj4.y - riy;
    const float dz = rj4.z - riz;
    const float rn = frcp(fmaxf(fsqrt(dx * dx + dy * dy + dz * dz), 1e-4f));
    float* cb = out + NB * MA + NB * MA * 3 +
                ((size_t)row * KSEL + k2) * (NOUT * 3) + o * 3;
    cb[0] = s * (dx * rn);
    cb[1] = s * (dy * rn);
    cb[2] = s * (dz * rn);
  }
}

extern "C" void kernel_launch(void* const* d_in, const int* in_sizes, int n_in,
                              void* d_out, int out_size, void* d_ws, size_t ws_size,
                              hipStream_t stream) {
  const int*   z   = (const int*)d_in[0];
  const float* r   = (const float*)d_in[1];
  const float* h   = (const float*)d_in[2];
  const float* Wa  = (const float*)d_in[3];
  const float* ba  = (const float*)d_in[4];
  const float* Wp1 = (const float*)d_in[5];
  const float* bp1 = (const float*)d_in[6];
  const float* Wp2 = (const float*)d_in[7];
  const float* bp2 = (const float*)d_in[8];
  float* out = (float*)d_out;

  float* a1 = (float*)d_ws;                 // 1024
  float* a2 = a1 + NB * MA;                 // 1024
  float* P  = a2 + NB * MA;                 // 1024*256
  float* Q  = P + (size_t)NB * MA * HID;    // 1024*256
  float4* r4 = (float4*)(Q + (size_t)NB * MA * HID);  // 1024 float4 (16 KB)

  prep_kernel<<<2 * NB * MA / 4, 256, 0, stream>>>(z, r, h, Wa, Wp1, out, a1, a2, P, Q, r4);
  main_kernel<<<NB * MA, 256, 0, stream>>>(r4, a1, a2, ba, P, Q, bp1, Wp2, bp2, out);
}

// Round 18
// 19.461 us; speedup vs baseline: 1.3104x; 1.0188x over previous
//
#include <hip/hip_runtime.h>
#include <hip/hip_bf16.h>
#include <math.h>

#define NB 4
#define MA 256
#define NFS 128
#define KSEL 8
#define HID 256
#define NOUT 32
#define RCUT 5.0f
#define PI_F 3.14159265358979323846f

__device__ __forceinline__ float frcp(float x) { return __builtin_amdgcn_rcpf(x); }
__device__ __forceinline__ float fsqrt(float x) { return __builtin_amdgcn_sqrtf(x); }

// Kernel 1: 512 blocks = (rowgroup 0..255) x (half 0..1).
// Block computes 4 rows x 256 cols of (half==0 ? P : Q) over full f=0..127.
__global__ __launch_bounds__(256) void prep_kernel(
    const int* __restrict__ z, const float* __restrict__ r,
    const float* __restrict__ h, const float* __restrict__ Wa,
    const float* __restrict__ Wp1,
    float* __restrict__ out,
    float* __restrict__ a1, float* __restrict__ a2,
    float* __restrict__ P, float* __restrict__ Q) {
  const int b = blockIdx.x;
  const int half = b & 1;
  const int rg = b >> 1;
  const int r0 = 4 * rg;
  const int t = threadIdx.x;
  const int wave = t >> 6, lane = t & 63;
  const int c = t & 63, fq = t >> 6;

  __shared__ __align__(16) float hsh[4][NFS];
  __shared__ __align__(16) float psum[4][4][HID];   // 16 KB

  ((float2*)hsh)[t] = ((const float2*)(h + (size_t)r0 * NFS))[t];
  __syncthreads();

  if (half == 0) {
    const float h0 = hsh[wave][lane], h1 = hsh[wave][lane + 64];
    float p1 = h0 * Wa[lane]       + h1 * Wa[lane + 64];
    float p2 = h0 * Wa[NFS + lane] + h1 * Wa[NFS + lane + 64];
#pragma unroll
    for (int off = 32; off > 0; off >>= 1) {
      p1 += __shfl_down(p1, off);
      p2 += __shfl_down(p2, off);
    }
    if (lane == 0) { a1[r0 + wave] = p1; a2[r0 + wave] = p2; }
    if (t < 4)  out[r0 + t] = (float)z[r0 + t];
    if (t < 12) out[NB * MA + r0 * 3 + t] = r[r0 * 3 + t];
  }

  const float* __restrict__ Wbase = Wp1 + (size_t)(half ? NFS : 0) * HID;
  float4 acc[4] = {make_float4(0,0,0,0), make_float4(0,0,0,0),
                   make_float4(0,0,0,0), make_float4(0,0,0,0)};
#pragma unroll 4
  for (int ff = 0; ff < 32; ++ff) {
    const int f = fq * 32 + ff;
    const float4 w = *(const float4*)&Wbase[(size_t)f * HID + 4 * c];
#pragma unroll
    for (int rr = 0; rr < 4; ++rr) {
      const float hv = hsh[rr][f];
      acc[rr].x = fmaf(hv, w.x, acc[rr].x);
      acc[rr].y = fmaf(hv, w.y, acc[rr].y);
      acc[rr].z = fmaf(hv, w.z, acc[rr].z);
      acc[rr].w = fmaf(hv, w.w, acc[rr].w);
    }
  }
#pragma unroll
  for (int rr = 0; rr < 4; ++rr) *(float4*)&psum[fq][rr][4 * c] = acc[rr];
  __syncthreads();

  {
    const int r2 = t >> 6, c2 = t & 63;
    float4 s = *(const float4*)&psum[0][r2][4 * c2];
#pragma unroll
    for (int q = 1; q < 4; ++q) {
      const float4 p = *(const float4*)&psum[q][r2][4 * c2];
      s.x += p.x; s.y += p.y; s.z += p.z; s.w += p.w;
    }
    float* dst = (half ? Q : P) + (size_t)(r0 + r2) * HID + 4 * c2;
    *(float4*)dst = s;
  }
}

// Kernel 2: one block per (n,i). g(LDS) -> top-8 in 4 rounds (top-2 butterfly +
// ballot index pair) -> hidden -> layer2 broadcast -> final. Base = 19.56us r12.
__global__ __launch_bounds__(256) void main_kernel(
    const int* __restrict__ z, const float* __restrict__ r,
    const float* __restrict__ a1g, const float* __restrict__ a2g,
    const float* __restrict__ ba,
    const float* __restrict__ Pg, const float* __restrict__ Qg,
    const float* __restrict__ bp1,
    const float* __restrict__ Wp2g, const float* __restrict__ bp2,
    float* __restrict__ out) {
  const int row = blockIdx.x;   // n*MA + i
  const int n = row >> 8;
  const int i = row & 255;
  const int tid = threadIdx.x;
  const int lane = tid & 63;

  __shared__ float gsh[MA];                            // 1 KB
  __shared__ __align__(16) float hid_sh[KSEL][HID];    // 8 KB
  __shared__ float psum2[8][KSEL][NOUT];               // 8 KB

  // layer-2 roles; one-pass Wp2 register staging issued EARLY (drains under g+topk)
  const int l2o = tid & 31;
  const int l2c = tid >> 5;
  float wreg[32];
#pragma unroll
  for (int j = 0; j < 32; ++j) wreg[j] = Wp2g[(size_t)(32 * l2c + j) * NOUT + l2o];

  // ---- g for all j (this thread's j = tid) ----
  const float rix = r[row * 3 + 0], riy = r[row * 3 + 1], riz = r[row * 3 + 2];
  {
    const int jg = n * MA + tid;
    const float dx = r[jg * 3 + 0] - rix;
    const float dy = r[jg * 3 + 1] - riy;
    const float dz = r[jg * 3 + 2] - riz;
    const float d = fsqrt(dx * dx + dy * dy + dz * dz);
    const int mi = (z[row] > -1) ? 1 : 0;
    const int mj = (z[jg] > -1) ? 1 : 0;
    const int mask = max(mi * mj - ((tid == i) ? 1 : 0), 0);
    float g = 0.0f;
    if (mask) {
      const float cf = 0.5f * (__cosf(PI_F * fminf(d, RCUT) / RCUT) + 1.0f);
      g = __expf(a1g[row] + cf * a2g[jg] + ba[0]);
    }
    gsh[tid] = g;
  }
  // hoisted independent loads (overlap with topk chain below)
  const float pi_h = Pg[(size_t)row * HID + tid];
  const float bb_h = bp1[tid];
  __syncthreads();

  // ---- ALL waves: denom + top-8 in 4 rounds (top-2 per round) ----
  float att[KSEL];
  int   idx[KSEL];
  {
    float v0 = gsh[lane];
    float v1 = gsh[lane + 64];
    float v2 = gsh[lane + 128];
    float v3 = gsh[lane + 192];
    float s = (v0 + v1) + (v2 + v3);
#pragma unroll
    for (int off = 32; off > 0; off >>= 1) s += __shfl_xor(s, off);
    const float rden = frcp(fmaxf(s, 1e-8f));
#pragma unroll
    for (int rr = 0; rr < 4; ++rr) {
      // per-lane top-2 of the 4 slots
      const float a1m = fmaxf(v0, v1), a2m = fminf(v0, v1);
      const float b1m = fmaxf(v2, v3), b2m = fminf(v2, v3);
      float m1 = fmaxf(a1m, b1m);
      float m2 = fmaxf(fminf(a1m, b1m), fmaxf(a2m, b2m));
      // butterfly top-2 all-reduce (2 independent shfl per level)
#pragma unroll
      for (int off = 32; off > 0; off >>= 1) {
        const float p1 = __shfl_xor(m1, off);
        const float p2 = __shfl_xor(m2, off);
        const float lo = fminf(m1, p1);
        m1 = fmaxf(m1, p1);
        m2 = fmaxf(lo, fmaxf(m2, p2));
      }
      // index for m1: smallest global index among v == m1
      unsigned long long c0 = __ballot(v0 == m1);
      unsigned long long c1 = __ballot(v1 == m1);
      unsigned long long c2 = __ballot(v2 == m1);
      unsigned long long c3 = __ballot(v3 == m1);
      int j0 = c0 ? __builtin_ctzll(c0)       : 1024;
      int j1 = c1 ? __builtin_ctzll(c1) + 64  : 1024;
      int j2 = c2 ? __builtin_ctzll(c2) + 128 : 1024;
      int j3 = c3 ? __builtin_ctzll(c3) + 192 : 1024;
      const int biA = min(min(j0, j1), min(j2, j3));
      // index for m2: if tied with m1, second-smallest of the same masks
      int biB;
      if (m2 == m1) {          // wave-uniform branch
        const int slotA = biA >> 6;
        const unsigned long long bit = 1ull << (biA & 63);
        if (slotA == 0) c0 &= ~bit;
        else if (slotA == 1) c1 &= ~bit;
        else if (slotA == 2) c2 &= ~bit;
        else c3 &= ~bit;
        j0 = c0 ? __builtin_ctzll(c0)       : 1024;
        j1 = c1 ? __builtin_ctzll(c1) + 64  : 1024;
        j2 = c2 ? __builtin_ctzll(c2) + 128 : 1024;
        j3 = c3 ? __builtin_ctzll(c3) + 192 : 1024;
        biB = min(min(j0, j1), min(j2, j3));
      } else {
        const unsigned long long d0 = __ballot(v0 == m2);
        const unsigned long long d1 = __ballot(v1 == m2);
        const unsigned long long d2 = __ballot(v2 == m2);
        const unsigned long long d3 = __ballot(v3 == m2);
        j0 = d0 ? __builtin_ctzll(d0)       : 1024;
        j1 = d1 ? __builtin_ctzll(d1) + 64  : 1024;
        j2 = d2 ? __builtin_ctzll(d2) + 128 : 1024;
        j3 = d3 ? __builtin_ctzll(d3) + 192 : 1024;
        biB = min(min(j0, j1), min(j2, j3));
      }
      att[2 * rr]     = m1 * rden;
      att[2 * rr + 1] = m2 * rden;
      idx[2 * rr]     = __builtin_amdgcn_readfirstlane(biA);
      idx[2 * rr + 1] = __builtin_amdgcn_readfirstlane(biB);
      // clear both winners
      {
        const int slot = biA >> 6, who = biA & 63;
        if (lane == who) {
          if (slot == 0) v0 = -1.0f; else if (slot == 1) v1 = -1.0f;
          else if (slot == 2) v2 = -1.0f; else v3 = -1.0f;
        }
      }
      {
        const int slot = biB >> 6, who = biB & 63;
        if (lane == who) {
          if (slot == 0) v0 = -1.0f; else if (slot == 1) v1 = -1.0f;
          else if (slot == 2) v2 = -1.0f; else v3 = -1.0f;
        }
      }
    }
  }

  // ---- hidden: hid[k][tid] = silu(att_k*(P+Q) + b) with rcp-silu ----
  {
#pragma unroll
    for (int k = 0; k < KSEL; k++) {
      const float q = Qg[(size_t)(n * MA + idx[k]) * HID + tid];
      const float x = att[k] * (pi_h + q) + bb_h;
      hid_sh[k][tid] = x * frcp(1.0f + __expf(-x));
    }
  }
  __syncthreads();

  // ---- layer 2, broadcast scheme ----
  {
    float acc[KSEL];
#pragma unroll
    for (int k = 0; k < KSEL; ++k) acc[k] = 0.0f;
#pragma unroll
    for (int k = 0; k < KSEL; ++k) {
      const float4* __restrict__ hrow = (const float4*)&hid_sh[k][32 * l2c];
#pragma unroll
      for (int j4 = 0; j4 < 8; ++j4) {
        const float4 hv = hrow[j4];    // uniform across 32-lane group -> broadcast
        acc[k] = fmaf(hv.x, wreg[4 * j4 + 0],
                 fmaf(hv.y, wreg[4 * j4 + 1],
                 fmaf(hv.z, wreg[4 * j4 + 2],
                 fmaf(hv.w, wreg[4 * j4 + 3], acc[k]))));
      }
    }
#pragma unroll
    for (int k = 0; k < KSEL; ++k) psum2[l2c][k][l2o] = acc[k];
  }
  __syncthreads();

  // ---- final: thread (k2 = tid>>5, o = tid&31); select-tree idx; rcp norm ----
  {
    const int k2 = tid >> 5;
    const int o = tid & 31;
    float s = bp2[o];
#pragma unroll
    for (int cc = 0; cc < 8; ++cc) s += psum2[cc][k2][o];
    const int j01 = (k2 & 1) ? idx[1] : idx[0];
    const int j23 = (k2 & 1) ? idx[3] : idx[2];
    const int j45 = (k2 & 1) ? idx[5] : idx[4];
    const int j67 = (k2 & 1) ? idx[7] : idx[6];
    const int j03 = (k2 & 2) ? j23 : j01;
    const int j47 = (k2 & 2) ? j67 : j45;
    const int jsel = (k2 & 4) ? j47 : j03;
    const int jg = n * MA + jsel;
    const float dx = r[jg * 3 + 0] - rix;
    const float dy = r[jg * 3 + 1] - riy;
    const float dz = r[jg * 3 + 2] - riz;
    const float rn = frcp(fmaxf(fsqrt(dx * dx + dy * dy + dz * dz), 1e-4f));
    float* cb = out + NB * MA + NB * MA * 3 +
                ((size_t)row * KSEL + k2) * (NOUT * 3) + o * 3;
    cb[0] = s * (dx * rn);
    cb[1] = s * (dy * rn);
    cb[2] = s * (dz * rn);
  }
}

extern "C" void kernel_launch(void* const* d_in, const int* in_sizes, int n_in,
                              void* d_out, int out_size, void* d_ws, size_t ws_size,
                              hipStream_t stream) {
  const int*   z   = (const int*)d_in[0];
  const float* r   = (const float*)d_in[1];
  const float* h   = (const float*)d_in[2];
  const float* Wa  = (const float*)d_in[3];
  const float* ba  = (const float*)d_in[4];
  const float* Wp1 = (const float*)d_in[5];
  const float* bp1 = (const float*)d_in[6];
  const float* Wp2 = (const float*)d_in[7];
  const float* bp2 = (const float*)d_in[8];
  float* out = (float*)d_out;

  float* a1 = (float*)d_ws;                 // 1024
  float* a2 = a1 + NB * MA;                 // 1024
  float* P  = a2 + NB * MA;                 // 1024*256
  float* Q  = P + (size_t)NB * MA * HID;    // 1024*256

  prep_kernel<<<2 * NB * MA / 4, 256, 0, stream>>>(z, r, h, Wa, Wp1, out, a1, a2, P, Q);
  main_kernel<<<NB * MA, 256, 0, stream>>>(z, r, a1, a2, ba, P, Q, bp1, Wp2, bp2, out);
}

// Round 20
// 19.391 us; speedup vs baseline: 1.3151x; 1.0036x over previous
//
#include <hip/hip_runtime.h>
#include <hip/hip_bf16.h>
#include <math.h>

#define NB 4
#define MA 256
#define NFS 128
#define KSEL 8
#define HID 256
#define NOUT 32
#define RCUT 5.0f
#define PI_F 3.14159265358979323846f

__device__ __forceinline__ float frcp(float x) { return __builtin_amdgcn_rcpf(x); }
__device__ __forceinline__ float fsqrt(float x) { return __builtin_amdgcn_sqrtf(x); }

// Kernel 1: 512 blocks = (rowgroup 0..255) x (half 0..1).
// Block computes 4 rows x 256 cols of (half==0 ? P : Q) over full f=0..127.
__global__ __launch_bounds__(256) void prep_kernel(
    const int* __restrict__ z, const float* __restrict__ r,
    const float* __restrict__ h, const float* __restrict__ Wa,
    const float* __restrict__ Wp1,
    float* __restrict__ out,
    float* __restrict__ a1, float* __restrict__ a2,
    float* __restrict__ P, float* __restrict__ Q) {
  const int b = blockIdx.x;
  const int half = b & 1;
  const int rg = b >> 1;
  const int r0 = 4 * rg;
  const int t = threadIdx.x;
  const int wave = t >> 6, lane = t & 63;
  const int c = t & 63, fq = t >> 6;

  __shared__ __align__(16) float hsh[4][NFS];
  __shared__ __align__(16) float psum[4][4][HID];   // 16 KB

  ((float2*)hsh)[t] = ((const float2*)(h + (size_t)r0 * NFS))[t];
  __syncthreads();

  if (half == 0) {
    const float h0 = hsh[wave][lane], h1 = hsh[wave][lane + 64];
    float p1 = h0 * Wa[lane]       + h1 * Wa[lane + 64];
    float p2 = h0 * Wa[NFS + lane] + h1 * Wa[NFS + lane + 64];
#pragma unroll
    for (int off = 32; off > 0; off >>= 1) {
      p1 += __shfl_down(p1, off);
      p2 += __shfl_down(p2, off);
    }
    if (lane == 0) { a1[r0 + wave] = p1; a2[r0 + wave] = p2; }
    if (t < 4)  out[r0 + t] = (float)z[r0 + t];
    if (t < 12) out[NB * MA + r0 * 3 + t] = r[r0 * 3 + t];
  }

  const float* __restrict__ Wbase = Wp1 + (size_t)(half ? NFS : 0) * HID;
  float4 acc[4] = {make_float4(0,0,0,0), make_float4(0,0,0,0),
                   make_float4(0,0,0,0), make_float4(0,0,0,0)};
#pragma unroll 4
  for (int ff = 0; ff < 32; ++ff) {
    const int f = fq * 32 + ff;
    const float4 w = *(const float4*)&Wbase[(size_t)f * HID + 4 * c];
#pragma unroll
    for (int rr = 0; rr < 4; ++rr) {
      const float hv = hsh[rr][f];
      acc[rr].x = fmaf(hv, w.x, acc[rr].x);
      acc[rr].y = fmaf(hv, w.y, acc[rr].y);
      acc[rr].z = fmaf(hv, w.z, acc[rr].z);
      acc[rr].w = fmaf(hv, w.w, acc[rr].w);
    }
  }
#pragma unroll
  for (int rr = 0; rr < 4; ++rr) *(float4*)&psum[fq][rr][4 * c] = acc[rr];
  __syncthreads();

  {
    const int r2 = t >> 6, c2 = t & 63;
    float4 s = *(const float4*)&psum[0][r2][4 * c2];
#pragma unroll
    for (int q = 1; q < 4; ++q) {
      const float4 p = *(const float4*)&psum[q][r2][4 * c2];
      s.x += p.x; s.y += p.y; s.z += p.z; s.w += p.w;
    }
    float* dst = (half ? Q : P) + (size_t)(r0 + r2) * HID + 4 * c2;
    *(float4*)dst = s;
  }
}

// Kernel 2: one block per (n,i). g(LDS) -> top-8 in 4 rounds (top-2 butterfly +
// ballot index pair) -> hidden -> layer2 broadcast -> final.
__global__ __launch_bounds__(256) void main_kernel(
    const int* __restrict__ z, const float* __restrict__ r,
    const float* __restrict__ a1g, const float* __restrict__ a2g,
    const float* __restrict__ ba,
    const float* __restrict__ Pg, const float* __restrict__ Qg,
    const float* __restrict__ bp1,
    const float* __restrict__ Wp2g, const float* __restrict__ bp2,
    float* __restrict__ out) {
  const int row = blockIdx.x;   // n*MA + i
  const int n = row >> 8;
  const int i = row & 255;
  const int tid = threadIdx.x;
  const int lane = tid & 63;

  __shared__ float gsh[MA];                            // 1 KB
  __shared__ __align__(16) float hid_sh[KSEL][HID];    // 8 KB
  __shared__ float psum2[8][KSEL][NOUT];               // 8 KB

  // layer-2 roles; one-pass Wp2 register staging issued EARLY (drains under g+topk)
  const int l2o = tid & 31;
  const int l2c = tid >> 5;
  float wreg[32];
#pragma unroll
  for (int j = 0; j < 32; ++j) wreg[j] = Wp2g[(size_t)(32 * l2c + j) * NOUT + l2o];

  // ---- g for all j (this thread's j = tid) ----
  const float rix = r[row * 3 + 0], riy = r[row * 3 + 1], riz = r[row * 3 + 2];
  {
    const int jg = n * MA + tid;
    const float dx = r[jg * 3 + 0] - rix;
    const float dy = r[jg * 3 + 1] - riy;
    const float dz = r[jg * 3 + 2] - riz;
    const float d = fsqrt(dx * dx + dy * dy + dz * dz);
    const int mi = (z[row] > -1) ? 1 : 0;
    const int mj = (z[jg] > -1) ? 1 : 0;
    const int mask = max(mi * mj - ((tid == i) ? 1 : 0), 0);
    float g = 0.0f;
    if (mask) {
      const float cf = 0.5f * (__cosf(PI_F * fminf(d, RCUT) / RCUT) + 1.0f);
      g = __expf(a1g[row] + cf * a2g[jg] + ba[0]);
    }
    gsh[tid] = g;
  }
  // hoisted independent loads (overlap with topk chain below)
  const float pi_h = Pg[(size_t)row * HID + tid];
  const float bb_h = bp1[tid];
  __syncthreads();

  // ---- ALL waves: denom + top-8 in 4 rounds (top-2 per round) ----
  float att[KSEL];
  int   idx[KSEL];
  {
    float v0 = gsh[lane];
    float v1 = gsh[lane + 64];
    float v2 = gsh[lane + 128];
    float v3 = gsh[lane + 192];
    float s = (v0 + v1) + (v2 + v3);
#pragma unroll
    for (int off = 32; off > 0; off >>= 1) s += __shfl_xor(s, off);
    const float rden = frcp(fmaxf(s, 1e-8f));
#pragma unroll
    for (int rr = 0; rr < 4; ++rr) {
      // per-lane top-2 of the 4 slots
      const float a1m = fmaxf(v0, v1), a2m = fminf(v0, v1);
      const float b1m = fmaxf(v2, v3), b2m = fminf(v2, v3);
      float m1 = fmaxf(a1m, b1m);
      float m2 = fmaxf(fminf(a1m, b1m), fmaxf(a2m, b2m));
      // butterfly top-2 all-reduce (2 independent shfl per level)
#pragma unroll
      for (int off = 32; off > 0; off >>= 1) {
        const float p1 = __shfl_xor(m1, off);
        const float p2 = __shfl_xor(m2, off);
        const float lo = fminf(m1, p1);
        m1 = fmaxf(m1, p1);
        m2 = fmaxf(lo, fmaxf(m2, p2));
      }
      // index for m1: smallest global index among v == m1
      unsigned long long c0 = __ballot(v0 == m1);
      unsigned long long c1 = __ballot(v1 == m1);
      unsigned long long c2 = __ballot(v2 == m1);
      unsigned long long c3 = __ballot(v3 == m1);
      int j0 = c0 ? __builtin_ctzll(c0)       : 1024;
      int j1 = c1 ? __builtin_ctzll(c1) + 64  : 1024;
      int j2 = c2 ? __builtin_ctzll(c2) + 128 : 1024;
      int j3 = c3 ? __builtin_ctzll(c3) + 192 : 1024;
      const int biA = min(min(j0, j1), min(j2, j3));
      // index for m2: if tied with m1, second-smallest of the same masks
      int biB;
      if (m2 == m1) {          // wave-uniform branch
        const int slotA = biA >> 6;
        const unsigned long long bit = 1ull << (biA & 63);
        if (slotA == 0) c0 &= ~bit;
        else if (slotA == 1) c1 &= ~bit;
        else if (slotA == 2) c2 &= ~bit;
        else c3 &= ~bit;
        j0 = c0 ? __builtin_ctzll(c0)       : 1024;
        j1 = c1 ? __builtin_ctzll(c1) + 64  : 1024;
        j2 = c2 ? __builtin_ctzll(c2) + 128 : 1024;
        j3 = c3 ? __builtin_ctzll(c3) + 192 : 1024;
        biB = min(min(j0, j1), min(j2, j3));
      } else {
        const unsigned long long d0 = __ballot(v0 == m2);
        const unsigned long long d1 = __ballot(v1 == m2);
        const unsigned long long d2 = __ballot(v2 == m2);
        const unsigned long long d3 = __ballot(v3 == m2);
        j0 = d0 ? __builtin_ctzll(d0)       : 1024;
        j1 = d1 ? __builtin_ctzll(d1) + 64  : 1024;
        j2 = d2 ? __builtin_ctzll(d2) + 128 : 1024;
        j3 = d3 ? __builtin_ctzll(d3) + 192 : 1024;
        biB = min(min(j0, j1), min(j2, j3));
      }
      att[2 * rr]     = m1 * rden;
      att[2 * rr + 1] = m2 * rden;
      idx[2 * rr]     = __builtin_amdgcn_readfirstlane(biA);
      idx[2 * rr + 1] = __builtin_amdgcn_readfirstlane(biB);
      // clear both winners
      {
        const int slot = biA >> 6, who = biA & 63;
        if (lane == who) {
          if (slot == 0) v0 = -1.0f; else if (slot == 1) v1 = -1.0f;
          else if (slot == 2) v2 = -1.0f; else v3 = -1.0f;
        }
      }
      {
        const int slot = biB >> 6, who = biB & 63;
        if (lane == who) {
          if (slot == 0) v0 = -1.0f; else if (slot == 1) v1 = -1.0f;
          else if (slot == 2) v2 = -1.0f; else v3 = -1.0f;
        }
      }
    }
  }

  // ---- hidden: hid[k][tid] = silu(att_k*(P+Q) + b) with rcp-silu ----
  {
#pragma unroll
    for (int k = 0; k < KSEL; k++) {
      const float q = Qg[(size_t)(n * MA + idx[k]) * HID + tid];
      const float x = att[k] * (pi_h + q) + bb_h;
      hid_sh[k][tid] = x * frcp(1.0f + __expf(-x));
    }
  }
  __syncthreads();

  // ---- layer 2, broadcast scheme ----
  {
    float acc[KSEL];
#pragma unroll
    for (int k = 0; k < KSEL; ++k) acc[k] = 0.0f;
#pragma unroll
    for (int k = 0; k < KSEL; ++k) {
      const float4* __restrict__ hrow = (const float4*)&hid_sh[k][32 * l2c];
#pragma unroll
      for (int j4 = 0; j4 < 8; ++j4) {
        const float4 hv = hrow[j4];    // uniform across 32-lane group -> broadcast
        acc[k] = fmaf(hv.x, wreg[4 * j4 + 0],
                 fmaf(hv.y, wreg[4 * j4 + 1],
                 fmaf(hv.z, wreg[4 * j4 + 2],
                 fmaf(hv.w, wreg[4 * j4 + 3], acc[k]))));
      }
    }
#pragma unroll
    for (int k = 0; k < KSEL; ++k) psum2[l2c][k][l2o] = acc[k];
  }
  __syncthreads();

  // ---- final: thread (k2 = tid>>5, o = tid&31); select-tree idx; rcp norm ----
  {
    const int k2 = tid >> 5;
    const int o = tid & 31;
    float s = bp2[o];
#pragma unroll
    for (int cc = 0; cc < 8; ++cc) s += psum2[cc][k2][o];
    const int j01 = (k2 & 1) ? idx[1] : idx[0];
    const int j23 = (k2 & 1) ? idx[3] : idx[2];
    const int j45 = (k2 & 1) ? idx[5] : idx[4];
    const int j67 = (k2 & 1) ? idx[7] : idx[6];
    const int j03 = (k2 & 2) ? j23 : j01;
    const int j47 = (k2 & 2) ? j67 : j45;
    const int jsel = (k2 & 4) ? j47 : j03;
    const int jg = n * MA + jsel;
    const float dx = r[jg * 3 + 0] - rix;
    const float dy = r[jg * 3 + 1] - riy;
    const float dz = r[jg * 3 + 2] - riz;
    const float rn = frcp(fmaxf(fsqrt(dx * dx + dy * dy + dz * dz), 1e-4f));
    float* cb = out + NB * MA + NB * MA * 3 +
                ((size_t)row * KSEL + k2) * (NOUT * 3) + o * 3;
    cb[0] = s * (dx * rn);
    cb[1] = s * (dy * rn);
    cb[2] = s * (dz * rn);
  }
}

extern "C" void kernel_launch(void* const* d_in, const int* in_sizes, int n_in,
                              void* d_out, int out_size, void* d_ws, size_t ws_size,
                              hipStream_t stream) {
  const int*   z   = (const int*)d_in[0];
  const float* r   = (const float*)d_in[1];
  const float* h   = (const float*)d_in[2];
  const float* Wa  = (const float*)d_in[3];
  const float* ba  = (const float*)d_in[4];
  const float* Wp1 = (const float*)d_in[5];
  const float* bp1 = (const float*)d_in[6];
  const float* Wp2 = (const float*)d_in[7];
  const float* bp2 = (const float*)d_in[8];
  float* out = (float*)d_out;

  float* a1 = (float*)d_ws;                 // 1024
  float* a2 = a1 + NB * MA;                 // 1024
  float* P  = a2 + NB * MA;                 // 1024*256
  float* Q  = P + (size_t)NB * MA * HID;    // 1024*256

  prep_kernel<<<2 * NB * MA / 4, 256, 0, stream>>>(z, r, h, Wa, Wp1, out, a1, a2, P, Q);
  main_kernel<<<NB * MA, 256, 0, stream>>>(z, r, a1, a2, ba, P, Q, bp1, Wp2, bp2, out);
}

// Round 21
// 19.367 us; speedup vs baseline: 1.3167x; 1.0012x over previous
//
#include <hip/hip_runtime.h>
#include <hip/hip_bf16.h>
#include <math.h>

#define NB 4
#define MA 256
#define NFS 128
#define KSEL 8
#define HID 256
#define NOUT 32
#define RCUT 5.0f
#define PI_F 3.14159265358979323846f

__device__ __forceinline__ float frcp(float x) { return __builtin_amdgcn_rcpf(x); }
__device__ __forceinline__ float fsqrt(float x) { return __builtin_amdgcn_sqrtf(x); }

// Kernel 1: 512 blocks = (rowgroup 0..255) x (half 0..1).
// Block computes 4 rows x 256 cols of (half==0 ? P : Q) over full f=0..127.
__global__ __launch_bounds__(256) void prep_kernel(
    const int* __restrict__ z, const float* __restrict__ r,
    const float* __restrict__ h, const float* __restrict__ Wa,
    const float* __restrict__ Wp1,
    float* __restrict__ out,
    float* __restrict__ a1, float* __restrict__ a2,
    float* __restrict__ P, float* __restrict__ Q) {
  const int b = blockIdx.x;
  const int half = b & 1;
  const int rg = b >> 1;
  const int r0 = 4 * rg;
  const int t = threadIdx.x;
  const int wave = t >> 6, lane = t & 63;
  const int c = t & 63, fq = t >> 6;

  __shared__ __align__(16) float hsh[4][NFS];
  __shared__ __align__(16) float psum[4][4][HID];   // 16 KB

  ((float2*)hsh)[t] = ((const float2*)(h + (size_t)r0 * NFS))[t];
  __syncthreads();

  if (half == 0) {
    const float h0 = hsh[wave][lane], h1 = hsh[wave][lane + 64];
    float p1 = h0 * Wa[lane]       + h1 * Wa[lane + 64];
    float p2 = h0 * Wa[NFS + lane] + h1 * Wa[NFS + lane + 64];
#pragma unroll
    for (int off = 32; off > 0; off >>= 1) {
      p1 += __shfl_down(p1, off);
      p2 += __shfl_down(p2, off);
    }
    if (lane == 0) { a1[r0 + wave] = p1; a2[r0 + wave] = p2; }
    if (t < 4)  out[r0 + t] = (float)z[r0 + t];
    if (t < 12) out[NB * MA + r0 * 3 + t] = r[r0 * 3 + t];
  }

  const float* __restrict__ Wbase = Wp1 + (size_t)(half ? NFS : 0) * HID;
  float4 acc[4] = {make_float4(0,0,0,0), make_float4(0,0,0,0),
                   make_float4(0,0,0,0), make_float4(0,0,0,0)};
#pragma unroll 4
  for (int ff = 0; ff < 32; ++ff) {
    const int f = fq * 32 + ff;
    const float4 w = *(const float4*)&Wbase[(size_t)f * HID + 4 * c];
#pragma unroll
    for (int rr = 0; rr < 4; ++rr) {
      const float hv = hsh[rr][f];
      acc[rr].x = fmaf(hv, w.x, acc[rr].x);
      acc[rr].y = fmaf(hv, w.y, acc[rr].y);
      acc[rr].z = fmaf(hv, w.z, acc[rr].z);
      acc[rr].w = fmaf(hv, w.w, acc[rr].w);
    }
  }
#pragma unroll
  for (int rr = 0; rr < 4; ++rr) *(float4*)&psum[fq][rr][4 * c] = acc[rr];
  __syncthreads();

  {
    const int r2 = t >> 6, c2 = t & 63;
    float4 s = *(const float4*)&psum[0][r2][4 * c2];
#pragma unroll
    for (int q = 1; q < 4; ++q) {
      const float4 p = *(const float4*)&psum[q][r2][4 * c2];
      s.x += p.x; s.y += p.y; s.z += p.z; s.w += p.w;
    }
    float* dst = (half ? Q : P) + (size_t)(r0 + r2) * HID + 4 * c2;
    *(float4*)dst = s;
  }
}

// Kernel 2: one block per (n,i). g(LDS) -> top-8 in 4 rounds (top-2 butterfly +
// ballot index pair, per-round Q prefetch) -> hidden -> layer2 broadcast -> final.
__global__ __launch_bounds__(256) void main_kernel(
    const int* __restrict__ z, const float* __restrict__ r,
    const float* __restrict__ a1g, const float* __restrict__ a2g,
    const float* __restrict__ ba,
    const float* __restrict__ Pg, const float* __restrict__ Qg,
    const float* __restrict__ bp1,
    const float* __restrict__ Wp2g, const float* __restrict__ bp2,
    float* __restrict__ out) {
  const int row = blockIdx.x;   // n*MA + i
  const int n = row >> 8;
  const int i = row & 255;
  const int tid = threadIdx.x;
  const int lane = tid & 63;

  __shared__ float gsh[MA];                            // 1 KB
  __shared__ __align__(16) float hid_sh[KSEL][HID];    // 8 KB
  __shared__ float psum2[8][KSEL][NOUT];               // 8 KB

  // layer-2 roles; one-pass Wp2 register staging issued EARLY (drains under g+topk)
  const int l2o = tid & 31;
  const int l2c = tid >> 5;
  float wreg[32];
#pragma unroll
  for (int j = 0; j < 32; ++j) wreg[j] = Wp2g[(size_t)(32 * l2c + j) * NOUT + l2o];

  // ---- g for all j (this thread's j = tid) ----
  const float rix = r[row * 3 + 0], riy = r[row * 3 + 1], riz = r[row * 3 + 2];
  {
    const int jg = n * MA + tid;
    const float dx = r[jg * 3 + 0] - rix;
    const float dy = r[jg * 3 + 1] - riy;
    const float dz = r[jg * 3 + 2] - riz;
    const float d = fsqrt(dx * dx + dy * dy + dz * dz);
    const int mi = (z[row] > -1) ? 1 : 0;
    const int mj = (z[jg] > -1) ? 1 : 0;
    const int mask = max(mi * mj - ((tid == i) ? 1 : 0), 0);
    float g = 0.0f;
    if (mask) {
      const float cf = 0.5f * (__cosf(PI_F * fminf(d, RCUT) / RCUT) + 1.0f);
      g = __expf(a1g[row] + cf * a2g[jg] + ba[0]);
    }
    gsh[tid] = g;
  }
  // hoisted independent loads (overlap with topk chain below)
  const float pi_h = Pg[(size_t)row * HID + tid];
  const float bb_h = bp1[tid];
  __syncthreads();

  // ---- ALL waves: denom + top-8 in 4 rounds (top-2 per round, Q prefetch) ----
  float att[KSEL];
  int   idx[KSEL];
  float qv[KSEL];
  {
    float v0 = gsh[lane];
    float v1 = gsh[lane + 64];
    float v2 = gsh[lane + 128];
    float v3 = gsh[lane + 192];
    float s = (v0 + v1) + (v2 + v3);
#pragma unroll
    for (int off = 32; off > 0; off >>= 1) s += __shfl_xor(s, off);
    const float rden = frcp(fmaxf(s, 1e-8f));
#pragma unroll
    for (int rr = 0; rr < 4; ++rr) {
      // per-lane top-2 of the 4 slots
      const float a1m = fmaxf(v0, v1), a2m = fminf(v0, v1);
      const float b1m = fmaxf(v2, v3), b2m = fminf(v2, v3);
      float m1 = fmaxf(a1m, b1m);
      float m2 = fmaxf(fminf(a1m, b1m), fmaxf(a2m, b2m));
      // butterfly top-2 all-reduce (2 independent shfl per level)
#pragma unroll
      for (int off = 32; off > 0; off >>= 1) {
        const float p1 = __shfl_xor(m1, off);
        const float p2 = __shfl_xor(m2, off);
        const float lo = fminf(m1, p1);
        m1 = fmaxf(m1, p1);
        m2 = fmaxf(lo, fmaxf(m2, p2));
      }
      // index for m1: smallest global index among v == m1
      unsigned long long c0 = __ballot(v0 == m1);
      unsigned long long c1 = __ballot(v1 == m1);
      unsigned long long c2 = __ballot(v2 == m1);
      unsigned long long c3 = __ballot(v3 == m1);
      int j0 = c0 ? __builtin_ctzll(c0)       : 1024;
      int j1 = c1 ? __builtin_ctzll(c1) + 64  : 1024;
      int j2 = c2 ? __builtin_ctzll(c2) + 128 : 1024;
      int j3 = c3 ? __builtin_ctzll(c3) + 192 : 1024;
      const int biA = min(min(j0, j1), min(j2, j3));
      // index for m2: if tied with m1, second-smallest of the same masks
      int biB;
      if (m2 == m1) {          // wave-uniform branch
        const int slotA = biA >> 6;
        const unsigned long long bit = 1ull << (biA & 63);
        if (slotA == 0) c0 &= ~bit;
        else if (slotA == 1) c1 &= ~bit;
        else if (slotA == 2) c2 &= ~bit;
        else c3 &= ~bit;
        j0 = c0 ? __builtin_ctzll(c0)       : 1024;
        j1 = c1 ? __builtin_ctzll(c1) + 64  : 1024;
        j2 = c2 ? __builtin_ctzll(c2) + 128 : 1024;
        j3 = c3 ? __builtin_ctzll(c3) + 192 : 1024;
        biB = min(min(j0, j1), min(j2, j3));
      } else {
        const unsigned long long d0 = __ballot(v0 == m2);
        const unsigned long long d1 = __ballot(v1 == m2);
        const unsigned long long d2 = __ballot(v2 == m2);
        const unsigned long long d3 = __ballot(v3 == m2);
        j0 = d0 ? __builtin_ctzll(d0)       : 1024;
        j1 = d1 ? __builtin_ctzll(d1) + 64  : 1024;
        j2 = d2 ? __builtin_ctzll(d2) + 128 : 1024;
        j3 = d3 ? __builtin_ctzll(d3) + 192 : 1024;
        biB = min(min(j0, j1), min(j2, j3));
      }
      att[2 * rr]     = m1 * rden;
      att[2 * rr + 1] = m2 * rden;
      idx[2 * rr]     = __builtin_amdgcn_readfirstlane(biA);
      idx[2 * rr + 1] = __builtin_amdgcn_readfirstlane(biB);
      // prefetch this round's Q rows NOW — latency hides under remaining rounds
      qv[2 * rr]     = Qg[(size_t)(n * MA + idx[2 * rr])     * HID + tid];
      qv[2 * rr + 1] = Qg[(size_t)(n * MA + idx[2 * rr + 1]) * HID + tid];
      // clear both winners
      {
        const int slot = biA >> 6, who = biA & 63;
        if (lane == who) {
          if (slot == 0) v0 = -1.0f; else if (slot == 1) v1 = -1.0f;
          else if (slot == 2) v2 = -1.0f; else v3 = -1.0f;
        }
      }
      {
        const int slot = biB >> 6, who = biB & 63;
        if (lane == who) {
          if (slot == 0) v0 = -1.0f; else if (slot == 1) v1 = -1.0f;
          else if (slot == 2) v2 = -1.0f; else v3 = -1.0f;
        }
      }
    }
  }

  // ---- hidden: hid[k][tid] = silu(att_k*(P+Q) + b) with rcp-silu ----
  {
#pragma unroll
    for (int k = 0; k < KSEL; k++) {
      const float x = att[k] * (pi_h + qv[k]) + bb_h;
      hid_sh[k][tid] = x * frcp(1.0f + __expf(-x));
    }
  }
  __syncthreads();

  // ---- layer 2, broadcast scheme ----
  {
    float acc[KSEL];
#pragma unroll
    for (int k = 0; k < KSEL; ++k) acc[k] = 0.0f;
#pragma unroll
    for (int k = 0; k < KSEL; ++k) {
      const float4* __restrict__ hrow = (const float4*)&hid_sh[k][32 * l2c];
#pragma unroll
      for (int j4 = 0; j4 < 8; ++j4) {
        const float4 hv = hrow[j4];    // uniform across 32-lane group -> broadcast
        acc[k] = fmaf(hv.x, wreg[4 * j4 + 0],
                 fmaf(hv.y, wreg[4 * j4 + 1],
                 fmaf(hv.z, wreg[4 * j4 + 2],
                 fmaf(hv.w, wreg[4 * j4 + 3], acc[k]))));
      }
    }
#pragma unroll
    for (int k = 0; k < KSEL; ++k) psum2[l2c][k][l2o] = acc[k];
  }
  __syncthreads();

  // ---- final: thread (k2 = tid>>5, o = tid&31); select-tree idx; rcp norm ----
  {
    const int k2 = tid >> 5;
    const int o = tid & 31;
    float s = bp2[o];
#pragma unroll
    for (int cc = 0; cc < 8; ++cc) s += psum2[cc][k2][o];
    const int j01 = (k2 & 1) ? idx[1] : idx[0];
    const int j23 = (k2 & 1) ? idx[3] : idx[2];
    const int j45 = (k2 & 1) ? idx[5] : idx[4];
    const int j67 = (k2 & 1) ? idx[7] : idx[6];
    const int j03 = (k2 & 2) ? j23 : j01;
    const int j47 = (k2 & 2) ? j67 : j45;
    const int jsel = (k2 & 4) ? j47 : j03;
    const int jg = n * MA + jsel;
    const float dx = r[jg * 3 + 0] - rix;
    const float dy = r[jg * 3 + 1] - riy;
    const float dz = r[jg * 3 + 2] - riz;
    const float rn = frcp(fmaxf(fsqrt(dx * dx + dy * dy + dz * dz), 1e-4f));
    float* cb = out + NB * MA + NB * MA * 3 +
                ((size_t)row * KSEL + k2) * (NOUT * 3) + o * 3;
    cb[0] = s * (dx * rn);
    cb[1] = s * (dy * rn);
    cb[2] = s * (dz * rn);
  }
}

extern "C" void kernel_launch(void* const* d_in, const int* in_sizes, int n_in,
                              void* d_out, int out_size, void* d_ws, size_t ws_size,
                              hipStream_t stream) {
  const int*   z   = (const int*)d_in[0];
  const float* r   = (const float*)d_in[1];
  const float* h   = (const float*)d_in[2];
  const float* Wa  = (const float*)d_in[3];
  const float* ba  = (const float*)d_in[4];
  const float* Wp1 = (const float*)d_in[5];
  const float* bp1 = (const float*)d_in[6];
  const float* Wp2 = (const float*)d_in[7];
  const float* bp2 = (const float*)d_in[8];
  float* out = (float*)d_out;

  float* a1 = (float*)d_ws;                 // 1024
  float* a2 = a1 + NB * MA;                 // 1024
  float* P  = a2 + NB * MA;                 // 1024*256
  float* Q  = P + (size_t)NB * MA * HID;    // 1024*256

  prep_kernel<<<2 * NB * MA / 4, 256, 0, stream>>>(z, r, h, Wa, Wp1, out, a1, a2, P, Q);
  main_kernel<<<NB * MA, 256, 0, stream>>>(z, r, a1, a2, ba, P, Q, bp1, Wp2, bp2, out);
}